// Round 1
// baseline (260.190 us; speedup 1.0000x reference)
//
#include <hip/hip_runtime.h>
#include <stdint.h>

typedef unsigned short u16;
typedef __attribute__((ext_vector_type(8))) short bf16x8;   // 8 bf16 = 4 VGPRs
typedef __attribute__((ext_vector_type(4))) float f32x4;

#define NUM_B 2
#define SEQ   2048
#define SEQP  2080      // padded V row stride
#define NH    16
#define HD    128
#define EMB   2048      // NH*HD
#define N3    6144      // 3*EMB
#define MM    4096      // NUM_B*SEQ
#define QT    64        // flash q-rows per block (2 waves)
#define WQ    32        // flash q-rows per wave
#define KT    32        // flash keys per k-tile
#define NTILE (SEQ / KT)

// ---- GEMM tile params (multi-phase counted-vmcnt template) ----
#define BM 128
#define BN 256
#define BK 64
#define NT_K (EMB / BK)   // 32 K-tiles

__device__ __forceinline__ u16 f2bf(float f) {
  union { float f; unsigned u; } c; c.f = f;
  return (u16)((c.u + 0x7FFFu + ((c.u >> 16) & 1u)) >> 16);   // RNE
}
__device__ __forceinline__ void async16(const void* g, void* l) {
  __builtin_amdgcn_global_load_lds(
      (const __attribute__((address_space(1))) void*)g,
      (__attribute__((address_space(3))) void*)l, 16, 0, 0);
}

#define GBAR()   asm volatile("s_barrier" ::: "memory")
#define WLGKM0() asm volatile("s_waitcnt lgkmcnt(0)" ::: "memory")

// ---------------- prep kernels ----------------

__global__ void k_cvt_bf16(const float* __restrict__ in, u16* __restrict__ out, int n4) {
  int i = blockIdx.x * blockDim.x + threadIdx.x;
  if (i >= n4) return;
  const float4 v = ((const float4*)in)[i];
  ushort4 o;
  o.x = f2bf(v.x); o.y = f2bf(v.y); o.z = f2bf(v.z); o.w = f2bf(v.w);
  ((ushort4*)out)[i] = o;
}

// W [EMB][N3] fp32 -> Wt [N3][EMB] bf16
__global__ void k_transpose_w(const float* __restrict__ W, u16* __restrict__ Wt) {
  __shared__ float t[32][33];
  int n0 = blockIdx.x * 32, k0 = blockIdx.y * 32;
  int tx = threadIdx.x, ty = threadIdx.y;
  #pragma unroll
  for (int i = ty; i < 32; i += 8)
    t[i][tx] = W[(size_t)(k0 + i) * N3 + n0 + tx];
  __syncthreads();
  #pragma unroll
  for (int i = ty; i < 32; i += 8)
    Wt[(size_t)(n0 + i) * EMB + k0 + tx] = f2bf(t[tx][i]);
}

// sincos table for t = s*HD + d; double-precision sincos matches numpy fp32 tables
__global__ void k_sincos(float2* __restrict__ tab) {
  int i = blockIdx.x * blockDim.x + threadIdx.x;   // 0 .. SEQ*HD-1
  double t = (double)i;
  tab[i] = make_float2((float)cos(t), (float)sin(t));
}

// ---------------- QKV GEMM: 128x256 tile, BK=64, 8 waves, 2-phase/K-tile ----------------
// Schedule per K-tile t (buf p = t&1), 2 phases:
//  ph0: ds_read B all (8 b128) + A half-0 (4) ; issue stage A(t+1)->buf[1-p]   (2 loads)
//       barrier ; lgkmcnt(0) ; setprio(1) ; 16 MFMA ; setprio(0) ; barrier
//  ph1: ds_read A half-1 (4)                 ; issue stage B(t+2)->buf[p]      (4 loads)
//       vmcnt(4)  <- lands ALL of tile t+1 (in-order FIFO), keeps t+2.B in flight
//       barrier ; lgkmcnt(0) ; setprio(1) ; 16 MFMA ; setprio(0) ; barrier
// LDS swizzle (T2): data for (row, quad) lives at slot (row, quad ^ (row&7));
// global_load_lds dest stays LINEAR, the XOR is applied to the per-lane GLOBAL
// source quad (involution), and to the ds_read quad. 8 consecutive lanes then
// hit 8 distinct 16B bank-quads -> conflict-free.
// Wave layout: 8 waves = 2(M) x 4(N); per-wave 64x64. N-frag strips remapped so
// each wave owns both halves of every RoPE pair: strip(nf) = (nf>>1)*64 +
// (wc&1)*32 + (nf&1)*16 within its head ((wc>>1) selects head of the 2 in BN).
__global__ __launch_bounds__(512, 2) void k_gemm_qkv(
    const u16* __restrict__ xb, const u16* __restrict__ wt,
    const float* __restrict__ bias, const float2* __restrict__ tab,
    u16* __restrict__ qb, u16* __restrict__ kb, u16* __restrict__ vbt)
{
  __shared__ __align__(16) u16 lsA[2][BM * BK];   // 16 KB x2
  __shared__ __align__(16) u16 lsB[2][BN * BK];   // 32 KB x2  (96 KB total)
  const int tid = threadIdx.x;            // 0..511
  const int wave = tid >> 6, lane = tid & 63;
  const int lq = lane & 15, lr = lane >> 4;
  const int wr = wave >> 2, wc = wave & 3;
  const int m0 = blockIdx.y * BM, n0 = blockIdx.x * BN;

  auto stageA = [&](int t, int buf) {     // 2 loads/thread, 16 KB
    const int kt = t * BK;
    #pragma unroll
    for (int ii = 0; ii < 2; ++ii) {
      int s = ii * 512 + tid;             // 16B slot 0..1023
      int row = s >> 3, gq = (s & 7) ^ (row & 7);
      async16(xb + (size_t)(m0 + row) * EMB + kt + gq * 8, &lsA[buf][s * 8]);
    }
  };
  auto stageB = [&](int t, int buf, int half) {   // 2 loads/thread, 16 KB
    const int kt = t * BK;
    #pragma unroll
    for (int ii = 0; ii < 2; ++ii) {
      int s = ii * 512 + tid;
      int row = s >> 3, gq = (s & 7) ^ (row & 7);
      async16(wt + (size_t)(n0 + half * 128 + row) * EMB + kt + gq * 8,
              &lsB[buf][half * 8192 + s * 8]);
    }
  };

  f32x4 acc[4][4];
  #pragma unroll
  for (int i = 0; i < 4; ++i)
    #pragma unroll
    for (int j = 0; j < 4; ++j)
      acc[i][j] = f32x4{0.f, 0.f, 0.f, 0.f};

  // per-lane LDS read offsets (u16 units)
  int rbase[4];
  #pragma unroll
  for (int nf = 0; nf < 4; ++nf)
    rbase[nf] = ((wc >> 1) * 128 + (nf >> 1) * 64 + (wc & 1) * 32 + (nf & 1) * 16 + lq) * BK;
  const int aRow0 = (wr * 64 + lq) * BK;
  int qsw[2];
  qsw[0] = ((0 + lr) ^ (lq & 7)) * 8;
  qsw[1] = ((4 + lr) ^ (lq & 7)) * 8;

  // prologue: tile0 (A+B) + tile1 (B) = 10 loads; vmcnt(4) -> oldest 6 = tile0
  stageA(0, 0); stageB(0, 0, 0); stageB(0, 0, 1);
  stageB(1, 1, 0); stageB(1, 1, 1);
  asm volatile("s_waitcnt vmcnt(4)" ::: "memory");
  GBAR();

  for (int t = 0; t < NT_K; ++t) {
    const int p = t & 1;
    const u16* Ap = lsA[p];
    const u16* Bp = lsB[p];
    bf16x8 bfr[4][2];

    #pragma unroll
    for (int q = 0; q < 2; ++q) {
      bf16x8 afr[2][2];
      if (q == 0) {
        #pragma unroll
        for (int nf = 0; nf < 4; ++nf)
          #pragma unroll
          for (int kk = 0; kk < 2; ++kk)
            bfr[nf][kk] = *(const bf16x8*)(Bp + rbase[nf] + qsw[kk]);
      }
      #pragma unroll
      for (int mfl = 0; mfl < 2; ++mfl)
        #pragma unroll
        for (int kk = 0; kk < 2; ++kk)
          afr[mfl][kk] = *(const bf16x8*)(Ap + aRow0 + (q * 32 + mfl * 16) * BK + qsw[kk]);

      if (q == 0) {
        if (t + 1 < NT_K) stageA(t + 1, 1 - p);   // buf[1-p].A free since t-1 done
      } else {
        if (t + 2 < NT_K) {
          stageB(t + 2, p, 0);                    // buf[p].B free after this tile's ph0
          stageB(t + 2, p, 1);
          asm volatile("s_waitcnt vmcnt(4)" ::: "memory");  // lands all of tile t+1
        } else if (t + 1 < NT_K) {
          asm volatile("s_waitcnt vmcnt(0)" ::: "memory");  // drain for last tile
        }
      }
      GBAR();
      WLGKM0();
      __builtin_amdgcn_s_setprio(1);
      #pragma unroll
      for (int kk = 0; kk < 2; ++kk)
        #pragma unroll
        for (int mfl = 0; mfl < 2; ++mfl)
          #pragma unroll
          for (int nf = 0; nf < 4; ++nf)
            acc[q * 2 + mfl][nf] = __builtin_amdgcn_mfma_f32_16x16x32_bf16(
                afr[mfl][kk], bfr[nf][kk], acc[q * 2 + mfl][nf], 0, 0, 0);
      __builtin_amdgcn_s_setprio(0);
      GBAR();
    }
  }

  // ---------------- epilogue (fused bias + RoPE / V-transpose) ----------------
  const int w = n0 >> 11;                  // 0=q, 1=k, 2=v (BN=256 divides 2048)
  const int h = ((n0 & 2047) >> 7) + (wc >> 1);
  float bb[4];
  int dloc[4];
  #pragma unroll
  for (int nf = 0; nf < 4; ++nf) {
    dloc[nf] = (nf >> 1) * 64 + (wc & 1) * 32 + (nf & 1) * 16 + lq;   // d within head
    bb[nf] = bias[n0 + (wc >> 1) * 128 + dloc[nf]];
  }

  if (w == 2) {
    // V: transpose to [B,H,D,SEQP], 4 consecutive s per 8B store
    #pragma unroll
    for (int mfg = 0; mfg < 4; ++mfg) {
      int mg0 = m0 + wr * 64 + mfg * 16 + lr * 4;
      int b = mg0 >> 11, s0 = mg0 & 2047;
      #pragma unroll
      for (int nf = 0; nf < 4; ++nf) {
        int d = dloc[nf];
        ushort4 pk;
        pk.x = f2bf(acc[mfg][nf][0] + bb[nf]);
        pk.y = f2bf(acc[mfg][nf][1] + bb[nf]);
        pk.z = f2bf(acc[mfg][nf][2] + bb[nf]);
        pk.w = f2bf(acc[mfg][nf][3] + bb[nf]);
        *(ushort4*)(vbt + ((size_t)(b * NH + h) * HD + d) * SEQP + s0) = pk;
      }
    }
  } else {
    u16* basep = (w == 0) ? qb : kb;
    const float qs = (w == 0) ? 0.12751569843736827f : 1.0f;  // log2(e)/sqrt(128) into q
    #pragma unroll
    for (int mfg = 0; mfg < 4; ++mfg)
      #pragma unroll
      for (int r = 0; r < 4; ++r) {
        int mg = m0 + wr * 64 + mfg * 16 + lr * 4 + r;
        int b = mg >> 11, s = mg & 2047;
        u16* dst = basep + ((size_t)(b * NH + h) * SEQ + s) * HD;
        #pragma unroll
        for (int nf = 0; nf < 2; ++nf) {
          int d1 = dloc[nf];                       // in [0,64); partner at d1+64
          float c1 = acc[mfg][nf][r]     + bb[nf];
          float c2 = acc[mfg][nf + 2][r] + bb[nf + 2];
          float2 s1 = tab[s * HD + d1];
          float2 s2 = tab[s * HD + d1 + 64];
          dst[d1]      = f2bf((c1 * s1.x - c2 * s1.y) * qs);
          dst[d1 + 64] = f2bf((c2 * s2.x + c1 * s2.y) * qs);
        }
      }
  }
}

// ---------------- flash attention (unchanged; round-4 structure + XCD-aware remap) ----------------
__global__ __launch_bounds__(128, 2) void k_flash(
    const u16* __restrict__ qb, const u16* __restrict__ kb,
    const u16* __restrict__ vbt, float* __restrict__ out)
{
  __shared__ __align__(16) u16 lsK[2][KT * HD];   // [key][d] 16B-grp ^= key&7    (8 KB x2)
  __shared__ __align__(16) u16 lsV[2][HD * KT];   // [d][key] 16B-grp ^= (d>>1)&3 (8 KB x2)
  __shared__ __align__(16) u16 lsP[2][WQ * KT];   // per-wave [qrow][key], 8B-grp ^= row&6

  const int tid = threadIdx.x;            // 0..127
  const int wave = tid >> 6, lane = tid & 63;
  const int lq = lane & 15, lr = lane >> 4;
  const int i = blockIdx.x;               // 0..1023
  const int xcd = i & 7, j = i >> 3;      // j: 0..127
  const int bh = xcd * 4 + (j >> 5);      // 4 heads per XCD
  const int q0 = (j & 31) * QT;
  const u16* Qg = qb + ((size_t)bh * SEQ + q0 + wave * WQ) * HD;
  const u16* Kg = kb + (size_t)bh * SEQ * HD;
  const u16* Vg = vbt + (size_t)bh * HD * SEQP;

  auto stage = [&](int tile, int buf) {
    const int k0 = tile * KT;
    #pragma unroll
    for (int ii = 0; ii < 4; ++ii) {
      int c = tid + ii * 128;
      int key = c >> 4, grp = c & 15;
      async16(Kg + (size_t)(k0 + key) * HD + ((grp ^ (key & 7)) * 8), lsK[buf] + c * 8);
    }
    #pragma unroll
    for (int ii = 0; ii < 4; ++ii) {
      int c = tid + ii * 128;
      int d = c >> 2, g2 = c & 3;
      async16(Vg + (size_t)d * SEQP + k0 + ((g2 ^ ((d >> 1) & 3)) * 8), lsV[buf] + c * 8);
    }
  };

  stage(0, 0);

  bf16x8 qf[2][4];
  #pragma unroll
  for (int qq = 0; qq < 2; ++qq)
    #pragma unroll
    for (int ks = 0; ks < 4; ++ks)
      qf[qq][ks] = *(const bf16x8*)(Qg + (size_t)(qq * 16 + lq) * HD + ks * 32 + lr * 8);

  f32x4 acc_o[2][8];
  float lsum[2] = {0.f, 0.f};
  #pragma unroll
  for (int mb = 0; mb < 2; ++mb)
    #pragma unroll
    for (int nb = 0; nb < 8; ++nb) acc_o[mb][nb] = f32x4{0.f, 0.f, 0.f, 0.f};

  for (int t = 0; t < NTILE; ++t) {
    const int p = t & 1;
    __syncthreads();                 // drains stage(t); all waves done with buf 1-p
    if (t + 1 < NTILE) stage(t + 1, 1 - p);

    // S^T = K Q^T : 32 keys x 32 q-rows per wave
    f32x4 sacc[2][2];
    #pragma unroll
    for (int kbi = 0; kbi < 2; ++kbi)
      #pragma unroll
      for (int qq = 0; qq < 2; ++qq) sacc[kbi][qq] = f32x4{0.f, 0.f, 0.f, 0.f};
    #pragma unroll
    for (int ks = 0; ks < 4; ++ks) {
      bf16x8 kf[2];
      #pragma unroll
      for (int kbi = 0; kbi < 2; ++kbi) {
        int key = kbi * 16 + lq;
        int g = (ks * 4 + lr) ^ (key & 7);
        kf[kbi] = *(const bf16x8*)(lsK[p] + key * HD + g * 8);
      }
      #pragma unroll
      for (int kbi = 0; kbi < 2; ++kbi)
        #pragma unroll
        for (int qq = 0; qq < 2; ++qq)
          sacc[kbi][qq] = __builtin_amdgcn_mfma_f32_16x16x32_bf16(kf[kbi], qf[qq][ks], sacc[kbi][qq], 0, 0, 0);
    }

    // P = exp2(S) (log2e folded into q); packed b64 writes (4 consecutive keys/lane)
    #pragma unroll
    for (int kbi = 0; kbi < 2; ++kbi)
      #pragma unroll
      for (int qq = 0; qq < 2; ++qq) {
        float p0 = __builtin_amdgcn_exp2f(sacc[kbi][qq][0]);
        float p1 = __builtin_amdgcn_exp2f(sacc[kbi][qq][1]);
        float p2 = __builtin_amdgcn_exp2f(sacc[kbi][qq][2]);
        float p3 = __builtin_amdgcn_exp2f(sacc[kbi][qq][3]);
        lsum[qq] += (p0 + p1) + (p2 + p3);
        int row = qq * 16 + lq;
        int g = kbi * 4 + lr;
        int gp = g ^ (row & 6);
        uint2 pk;
        pk.x = (uint32_t)f2bf(p0) | ((uint32_t)f2bf(p1) << 16);
        pk.y = (uint32_t)f2bf(p2) | ((uint32_t)f2bf(p3) << 16);
        *(uint2*)(lsP[wave] + row * KT + gp * 4) = pk;
      }

    // O += P V
    bf16x8 ap[2];
    #pragma unroll
    for (int mb = 0; mb < 2; ++mb) {
      int row = mb * 16 + lq;
      int gp = (2 * lr) ^ (row & 6);
      ap[mb] = *(const bf16x8*)(lsP[wave] + row * KT + gp * 4);
    }
    #pragma unroll
    for (int nb = 0; nb < 8; ++nb) {
      int d = nb * 16 + lq;
      int g2 = lr ^ ((d >> 1) & 3);
      bf16x8 bv = *(const bf16x8*)(lsV[p] + d * KT + g2 * 8);
      #pragma unroll
      for (int mb = 0; mb < 2; ++mb)
        acc_o[mb][nb] = __builtin_amdgcn_mfma_f32_16x16x32_bf16(ap[mb], bv[0] == bv[0] ? bv : bv, acc_o[mb][nb], 0, 0, 0);
    }
  }

  float inv[2];
  #pragma unroll
  for (int qq = 0; qq < 2; ++qq) {
    float s = lsum[qq];
    s += __shfl_xor(s, 16);
    s += __shfl_xor(s, 32);
    inv[qq] = 1.0f / s;
  }
  const int b = bh >> 4, h = bh & 15;
  #pragma unroll
  for (int mb = 0; mb < 2; ++mb)
    #pragma unroll
    for (int r = 0; r < 4; ++r) {
      float iv = __shfl(inv[mb], lr * 4 + r);
      int row = wave * WQ + mb * 16 + lr * 4 + r;
      int sq = q0 + row;
      float* op = out + (((size_t)b * SEQ + sq) * NH + h) * HD;
      #pragma unroll
      for (int nb = 0; nb < 8; ++nb)
        op[nb * 16 + lq] = acc_o[mb][nb][r] * iv;
    }
}

// ---------------- launch ----------------

extern "C" void kernel_launch(void* const* d_in, const int* in_sizes, int n_in,
                              void* d_out, int out_size, void* d_ws, size_t ws_size,
                              hipStream_t stream) {
  (void)in_sizes; (void)n_in; (void)out_size; (void)ws_size;
  const float* x    = (const float*)d_in[0];
  const float* W    = (const float*)d_in[1];
  const float* bias = (const float*)d_in[2];
  float* out = (float*)d_out;

  char* p = (char*)d_ws;
  u16* xb  = (u16*)p;  p += (size_t)MM * EMB * 2;                     // 16.8 MB
  u16* wt  = (u16*)p;  p += (size_t)N3 * EMB * 2;                     // 25.2 MB
  u16* qb  = (u16*)p;  p += (size_t)NUM_B * NH * SEQ * HD * 2;        // 16.8 MB
  u16* kb  = (u16*)p;  p += (size_t)NUM_B * NH * SEQ * HD * 2;        // 16.8 MB
  u16* vbt = (u16*)p;  p += (size_t)NUM_B * NH * HD * SEQP * 2;       // 17.0 MB
  float2* tab = (float2*)p;                                           // 2.1 MB

  k_cvt_bf16<<<(MM * EMB / 4 + 255) / 256, 256, 0, stream>>>(x, xb, MM * EMB / 4);
  k_transpose_w<<<dim3(N3 / 32, EMB / 32), dim3(32, 8), 0, stream>>>(W, wt);
  k_sincos<<<(SEQ * HD) / 256, 256, 0, stream>>>(tab);
  k_gemm_qkv<<<dim3(N3 / BN, MM / BM), 512, 0, stream>>>(xb, wt, bias, tab, qb, kb, vbt);
  k_flash<<<SEQ / QT * NUM_B * NH, 128, 0, stream>>>(qb, kb, vbt, out);
}